// Round 2
// baseline (1491.216 us; speedup 1.0000x reference)
//
#include <hip/hip_runtime.h>
#include <hip/hip_bf16.h>

#define NNODES 20000
#define NEDGES 640000
#define NB 50
#define NF 128

typedef unsigned int uint_t;

__device__ __forceinline__ float lo16(uint_t u) { return __uint_as_float(u << 16); }
__device__ __forceinline__ float hi16(uint_t u) { return __uint_as_float(u & 0xffff0000u); }

// fp32 -> bf16 bits (round to nearest even), returned in low 16 bits
__device__ __forceinline__ uint_t f2bf(float f) {
    uint_t u = __float_as_uint(f);
    return (u + 0x7fffu + ((u >> 16) & 1u)) >> 16;
}

// shifted softplus: log(1+exp(x)) - log(2), numerically stable
__device__ __forceinline__ float ssp_f(float x) {
    return fmaxf(x, 0.0f) + log1pf(expf(-fabsf(x))) - 0.6931471805599453f;
}

// ---------------- zero the aggregation buffer (capture-safe) ----------------
__global__ __launch_bounds__(256) void k_zero(float4* __restrict__ p) {
    int i = blockIdx.x * 256 + threadIdx.x;   // grid 2500*256 = 640000 float4 = 2.56M floats exactly
    p[i] = make_float4(0.f, 0.f, 0.f, 0.f);
}

// ---------------- generic Y = act(X @ W + b), K=N=128, X/Y/W/b fp32 ----------------
// W is fp32 [128][128] row-major in global; packed into LDS as bf16 pairs (two k rows per uint).
template<bool DO_SSP, bool HAS_BIAS>
__global__ __launch_bounds__(256) void k_mm(const float* __restrict__ X,
                                            const float* __restrict__ W,
                                            const float* __restrict__ bias,
                                            float* __restrict__ Y, int nrows)
{
    __shared__ uint_t swp[64 * NF];              // 32 KB packed bf16 weights
    __shared__ alignas(16) float sx[2][4][NF];   // 4 KB staged input rows
    const int tid = threadIdx.x;
    for (int i = tid; i < 64 * NF; i += 256) {
        int p = i >> 7, ff = i & 127;
        uint_t lo = f2bf(W[(2 * p) * NF + ff]);
        uint_t hi = f2bf(W[(2 * p + 1) * NF + ff]);
        swp[i] = lo | (hi << 16);
    }
    const int g = tid >> 7, f = tid & 127;
    const float rb = HAS_BIAS ? bias[f] : 0.0f;
    for (int it = 0; it < 4; ++it) {
        int rbase = blockIdx.x * 32 + it * 8 + g * 4;
        __syncthreads();
        #pragma unroll
        for (int e = 0; e < 4; ++e) {
            int r = rbase + e;
            sx[g][e][f] = (r < nrows) ? X[r * NF + f] : 0.0f;
        }
        __syncthreads();
        float acc[4] = {rb, rb, rb, rb};
        #pragma unroll 8
        for (int k4 = 0; k4 < 32; ++k4) {
            float a[4][4];
            #pragma unroll
            for (int e = 0; e < 4; ++e) {
                float4 v = reinterpret_cast<const float4*>(&sx[g][e][0])[k4];
                a[e][0] = v.x; a[e][1] = v.y; a[e][2] = v.z; a[e][3] = v.w;
            }
            uint_t u0 = swp[(2 * k4) * NF + f];
            uint_t u1 = swp[(2 * k4 + 1) * NF + f];
            float w0 = lo16(u0), w1 = hi16(u0), w2 = lo16(u1), w3 = hi16(u1);
            #pragma unroll
            for (int e = 0; e < 4; ++e)
                acc[e] += a[e][0]*w0 + a[e][1]*w1 + a[e][2]*w2 + a[e][3]*w3;
        }
        #pragma unroll
        for (int e = 0; e < 4; ++e) {
            int r = rbase + e;
            if (r < nrows) {
                float o = DO_SSP ? ssp_f(acc[e]) : acc[e];
                Y[r * NF + f] = o;
            }
        }
    }
}

// ---------------- fused per-edge filter MLP + CFConv gather/scatter ----------------
// 512 threads = 4 groups x 128 filters; each group handles 4 edges per iteration.
// Grid must be 500 blocks: 500 * 1280 = 640000, and 1280 % 16 == 0 (no tail).
__global__ __launch_bounds__(512) void k_edge(
    const int* __restrict__ esrc, const int* __restrict__ edst,
    const float* __restrict__ ew, const float* __restrict__ ea,
    const float* __restrict__ w1, const float* __restrict__ b1,
    const float* __restrict__ w2, const float* __restrict__ b2,
    const float* __restrict__ h, float* __restrict__ agg)
{
    __shared__ uint_t sw1p[26 * NF];              // 13 KB: basis pairs, rows 50..51 zero-padded
    __shared__ uint_t sw2p[64 * NF];              // 32 KB
    __shared__ alignas(16) float sea[4][4][56];   // 3.5 KB, pads >=50 zeroed
    __shared__ alignas(16) float st1[4][4][NF];   // 8 KB
    __shared__ float sC[16];
    __shared__ int ssrc[16], sdst[16];

    const int tid = threadIdx.x;
    for (int i = tid; i < 26 * NF; i += 512) {
        int p = i >> 7, ff = i & 127;
        int k0 = 2 * p, k1 = 2 * p + 1;
        uint_t lo = (k0 < NB) ? f2bf(w1[k0 * NF + ff]) : 0u;
        uint_t hi = (k1 < NB) ? f2bf(w1[k1 * NF + ff]) : 0u;
        sw1p[i] = lo | (hi << 16);
    }
    for (int i = tid; i < 64 * NF; i += 512) {
        int p = i >> 7, ff = i & 127;
        uint_t lo = f2bf(w2[(2 * p) * NF + ff]);
        uint_t hi = f2bf(w2[(2 * p + 1) * NF + ff]);
        sw2p[i] = lo | (hi << 16);
    }
    const int g = tid >> 7, f = tid & 127;
    const float rb1 = b1[f];
    const float rb2 = b2[f];

    const int chunk = NEDGES / 500;          // 1280
    const int e0 = blockIdx.x * chunk;
    const int e1 = e0 + chunk;

    for (int ebase = e0; ebase < e1; ebase += 16) {
        __syncthreads();
        if (tid < 16) {
            int e = ebase + tid;
            ssrc[tid] = esrc[e];
            sdst[tid] = edst[e];
            sC[tid] = 0.5f * (cosf(ew[e] * 0.31415926535897931f) + 1.0f);
        }
        if (f < 56) {
            #pragma unroll
            for (int e = 0; e < 4; ++e) {
                int eg = ebase + g * 4 + e;
                sea[g][e][f] = (f < NB) ? ea[eg * NB + f] : 0.0f;
            }
        }
        __syncthreads();

        // layer 1: t1 = ssp(ea @ w1 + b1)
        float t1[4] = {rb1, rb1, rb1, rb1};
        #pragma unroll
        for (int b4 = 0; b4 < 13; ++b4) {
            float a[4][4];
            #pragma unroll
            for (int e = 0; e < 4; ++e) {
                float4 v = reinterpret_cast<const float4*>(&sea[g][e][0])[b4];
                a[e][0] = v.x; a[e][1] = v.y; a[e][2] = v.z; a[e][3] = v.w;
            }
            uint_t u0 = sw1p[(2 * b4) * NF + f];
            uint_t u1 = sw1p[(2 * b4 + 1) * NF + f];
            float w0 = lo16(u0), w1v = hi16(u0), w2v = lo16(u1), w3v = hi16(u1);
            #pragma unroll
            for (int e = 0; e < 4; ++e)
                t1[e] += a[e][0]*w0 + a[e][1]*w1v + a[e][2]*w2v + a[e][3]*w3v;
        }
        #pragma unroll
        for (int e = 0; e < 4; ++e) st1[g][e][f] = ssp_f(t1[e]);
        __syncthreads();

        // layer 2: W = (t1 @ w2 + b2) * C ; msg = h[src]*W ; agg[dst] += msg
        float t2[4] = {rb2, rb2, rb2, rb2};
        #pragma unroll 8
        for (int k4 = 0; k4 < 32; ++k4) {
            float a[4][4];
            #pragma unroll
            for (int e = 0; e < 4; ++e) {
                float4 v = reinterpret_cast<const float4*>(&st1[g][e][0])[k4];
                a[e][0] = v.x; a[e][1] = v.y; a[e][2] = v.z; a[e][3] = v.w;
            }
            uint_t u0 = sw2p[(2 * k4) * NF + f];
            uint_t u1 = sw2p[(2 * k4 + 1) * NF + f];
            float w0 = lo16(u0), w1v = hi16(u0), w2v = lo16(u1), w3v = hi16(u1);
            #pragma unroll
            for (int e = 0; e < 4; ++e)
                t2[e] += a[e][0]*w0 + a[e][1]*w1v + a[e][2]*w2v + a[e][3]*w3v;
        }
        #pragma unroll
        for (int e = 0; e < 4; ++e) {
            int li = g * 4 + e;
            float val = t2[e] * sC[li];
            float hs = h[ssrc[li] * NF + f];
            atomicAdd(&agg[sdst[li] * NF + f], val * hs);
        }
    }
}

extern "C" void kernel_launch(void* const* d_in, const int* in_sizes, int n_in,
                              void* d_out, int out_size, void* d_ws, size_t ws_size,
                              hipStream_t stream) {
    const float* x    = (const float*)d_in[0];   // [20000,128] fp32
    const int*   eidx = (const int*)d_in[1];     // [2,640000] int32
    const float* ew   = (const float*)d_in[2];   // [640000] fp32
    const float* ea   = (const float*)d_in[3];   // [640000,50] fp32
    const float* w1   = (const float*)d_in[4];   // [50,128]
    const float* b1   = (const float*)d_in[5];   // [128]
    const float* w2   = (const float*)d_in[6];   // [128,128]
    const float* b2   = (const float*)d_in[7];   // [128]
    const float* l1w  = (const float*)d_in[8];   // [128,128]
    const float* l2w  = (const float*)d_in[9];   // [128,128]
    const float* l2b  = (const float*)d_in[10];  // [128]
    const float* lw   = (const float*)d_in[11];  // [128,128]
    const float* lb   = (const float*)d_in[12];  // [128]
    (void)in_sizes; (void)n_in; (void)out_size; (void)ws_size;

    float* h   = (float*)d_ws;                                    // 10.24 MB
    float* agg = (float*)((char*)d_ws + (size_t)NNODES * NF * 4);  // 10.24 MB
    float* tmp = h;  // h is dead after k_edge; reuse for the tail MLP

    hipLaunchKernelGGL(k_zero, dim3(2500), dim3(256), 0, stream, (float4*)agg);
    // h = x @ lin1_w
    hipLaunchKernelGGL((k_mm<false, false>), dim3(625), dim3(256), 0, stream,
                       x, l1w, (const float*)nullptr, h, NNODES);
    // fused edge MLP + CFConv scatter
    hipLaunchKernelGGL(k_edge, dim3(500), dim3(512), 0, stream,
                       eidx, eidx + NEDGES, ew, ea, w1, b1, w2, b2, h, agg);
    // tmp = ssp(agg @ lin2_w + lin2_b)
    hipLaunchKernelGGL((k_mm<true, true>), dim3(625), dim3(256), 0, stream,
                       agg, l2w, l2b, tmp, NNODES);
    // out = tmp @ lin_w + lin_b   (fp32 output)
    hipLaunchKernelGGL((k_mm<false, true>), dim3(625), dim3(256), 0, stream,
                       tmp, lw, lb, (float*)d_out, NNODES);
}

// Round 3
// 879.578 us; speedup vs baseline: 1.6954x; 1.6954x over previous
//
#include <hip/hip_runtime.h>
#include <hip/hip_bf16.h>

#define NNODES 20000
#define NEDGES 640000
#define NB 50
#define NF 128

typedef unsigned int uint_t;
typedef unsigned short ushort_t;

typedef __bf16 bf16x8 __attribute__((ext_vector_type(8)));
typedef float f32x4 __attribute__((ext_vector_type(4)));

__device__ __forceinline__ float lo16(uint_t u) { return __uint_as_float(u << 16); }
__device__ __forceinline__ float hi16(uint_t u) { return __uint_as_float(u & 0xffff0000u); }

// fp32 -> bf16 bits (round to nearest even), returned in low 16 bits
__device__ __forceinline__ uint_t f2bf(float f) {
    uint_t u = __float_as_uint(f);
    return (u + 0x7fffu + ((u >> 16) & 1u)) >> 16;
}

// shifted softplus: log(1+exp(x)) - log(2), numerically stable
__device__ __forceinline__ float ssp_f(float x) {
    return fmaxf(x, 0.0f) + log1pf(expf(-fabsf(x))) - 0.6931471805599453f;
}

// ---------------- zero the aggregation buffer (capture-safe) ----------------
__global__ __launch_bounds__(256) void k_zero(float4* __restrict__ p) {
    int i = blockIdx.x * 256 + threadIdx.x;   // grid 2500*256 = 640000 float4 = 2.56M floats exactly
    p[i] = make_float4(0.f, 0.f, 0.f, 0.f);
}

// ---------------- generic Y = act(X @ W + b), K=N=128, fp32 io, bf16 weights in LDS ----------------
template<bool DO_SSP, bool HAS_BIAS>
__global__ __launch_bounds__(256) void k_mm(const float* __restrict__ X,
                                            const float* __restrict__ W,
                                            const float* __restrict__ bias,
                                            float* __restrict__ Y, int nrows)
{
    __shared__ uint_t swp[64 * NF];              // 32 KB packed bf16 weights
    __shared__ alignas(16) float sx[2][4][NF];   // 4 KB staged input rows
    const int tid = threadIdx.x;
    for (int i = tid; i < 64 * NF; i += 256) {
        int p = i >> 7, ff = i & 127;
        uint_t lo = f2bf(W[(2 * p) * NF + ff]);
        uint_t hi = f2bf(W[(2 * p + 1) * NF + ff]);
        swp[i] = lo | (hi << 16);
    }
    const int g = tid >> 7, f = tid & 127;
    const float rb = HAS_BIAS ? bias[f] : 0.0f;
    for (int it = 0; it < 4; ++it) {
        int rbase = blockIdx.x * 32 + it * 8 + g * 4;
        __syncthreads();
        #pragma unroll
        for (int e = 0; e < 4; ++e) {
            int r = rbase + e;
            sx[g][e][f] = (r < nrows) ? X[r * NF + f] : 0.0f;
        }
        __syncthreads();
        float acc[4] = {rb, rb, rb, rb};
        #pragma unroll 8
        for (int k4 = 0; k4 < 32; ++k4) {
            float a[4][4];
            #pragma unroll
            for (int e = 0; e < 4; ++e) {
                float4 v = reinterpret_cast<const float4*>(&sx[g][e][0])[k4];
                a[e][0] = v.x; a[e][1] = v.y; a[e][2] = v.z; a[e][3] = v.w;
            }
            uint_t u0 = swp[(2 * k4) * NF + f];
            uint_t u1 = swp[(2 * k4 + 1) * NF + f];
            float w0 = lo16(u0), w1 = hi16(u0), w2 = lo16(u1), w3 = hi16(u1);
            #pragma unroll
            for (int e = 0; e < 4; ++e)
                acc[e] += a[e][0]*w0 + a[e][1]*w1 + a[e][2]*w2 + a[e][3]*w3;
        }
        #pragma unroll
        for (int e = 0; e < 4; ++e) {
            int r = rbase + e;
            if (r < nrows) {
                float o = DO_SSP ? ssp_f(acc[e]) : acc[e];
                Y[r * NF + f] = o;
            }
        }
    }
}

// ---------------- fused edge MLP (MFMA) + CFConv gather/scatter ----------------
// 256 threads = 4 waves. Each wave owns 32 filters (2 N-tiles of 16).
// Each block-iteration processes 32 edges (2 M-tiles of 16).
// Weight B-fragments are loop-invariant -> held in VGPRs.
// Grid MUST be 1000 blocks: 1000 * 640 = 640000 edges, 20 iters of 32.
__global__ __launch_bounds__(256) void k_edge(
    const int* __restrict__ esrc, const int* __restrict__ edst,
    const float* __restrict__ ew, const float* __restrict__ ea,
    const float* __restrict__ w1, const float* __restrict__ b1,
    const float* __restrict__ w2, const float* __restrict__ b2,
    const float* __restrict__ h, float* __restrict__ agg)
{
    __shared__ alignas(16) ushort_t sea[32 * 72];    // [edge][k<64], row pad 72 bf16 = 144 B (4k%32 banks, 2-way free)
    __shared__ alignas(16) ushort_t st1[32 * 136];   // [edge][filter<128], row pad 136 bf16 = 272 B
    __shared__ float sC[32];
    __shared__ int ssrc[32], sdst[32];

    const int tid  = threadIdx.x;
    const int wv   = tid >> 6;        // wave 0..3
    const int lane = tid & 63;
    const int col  = lane & 15;       // MFMA col / A-row index
    const int quad = lane >> 4;

    // zero sea once: k in [50,72) must stay 0 forever (staging only writes k<50)
    for (int i = tid; i < 32 * 72; i += 256) sea[i] = 0;

    // ---- loop-invariant weight fragments into registers ----
    // B-layout for mfma_f32_16x16x32_bf16: lane holds B[k=quad*8+j][n=lane&15]
    bf16x8 w1f[2][2];   // [ntile][kchunk]  K=64 (50 + zero pad)
    bf16x8 w2f[2][4];   // [ntile][kchunk]  K=128
    float rb1[2], rb2[2];
    #pragma unroll
    for (int nt = 0; nt < 2; ++nt) {
        int n = wv * 32 + nt * 16 + col;
        rb1[nt] = b1[n];
        rb2[nt] = b2[n];
        #pragma unroll
        for (int kc = 0; kc < 2; ++kc)
            #pragma unroll
            for (int j = 0; j < 8; ++j) {
                int k = kc * 32 + quad * 8 + j;
                w1f[nt][kc][j] = (__bf16)((k < NB) ? w1[k * NF + n] : 0.0f);
            }
        #pragma unroll
        for (int kc = 0; kc < 4; ++kc)
            #pragma unroll
            for (int j = 0; j < 8; ++j) {
                int k = kc * 32 + quad * 8 + j;
                w2f[nt][kc][j] = (__bf16)w2[k * NF + n];
            }
    }

    const int e0 = blockIdx.x * 640;

    for (int it = 0; it < 20; ++it) {
        const int ebase = e0 + it * 32;
        __syncthreads();   // protect sea/st1/sC from previous iteration's readers
        // stage edge_attr -> bf16 (coalesced: i is contiguous over ea)
        for (int i = tid; i < 32 * NB; i += 256) {
            int e = i / NB;                 // compiler magic-div
            int k = i - e * NB;
            sea[e * 72 + k] = (ushort_t)f2bf(ea[(size_t)ebase * NB + i]);
        }
        if (tid < 32) {
            int e = ebase + tid;
            ssrc[tid] = esrc[e];
            sdst[tid] = edst[e];
            sC[tid]   = 0.5f * (cosf(ew[e] * 0.31415926535897931f) + 1.0f);
        }
        __syncthreads();

        // ---- layer 1: t1 = ssp(ea @ w1 + b1) ----
        f32x4 acc1[2][2];
        #pragma unroll
        for (int mt = 0; mt < 2; ++mt)
            #pragma unroll
            for (int nt = 0; nt < 2; ++nt)
                acc1[mt][nt] = f32x4{rb1[nt], rb1[nt], rb1[nt], rb1[nt]};
        #pragma unroll
        for (int kc = 0; kc < 2; ++kc) {
            bf16x8 af[2];
            #pragma unroll
            for (int mt = 0; mt < 2; ++mt)
                af[mt] = *reinterpret_cast<const bf16x8*>(&sea[(mt * 16 + col) * 72 + kc * 32 + quad * 8]);
            #pragma unroll
            for (int mt = 0; mt < 2; ++mt)
                #pragma unroll
                for (int nt = 0; nt < 2; ++nt)
                    acc1[mt][nt] = __builtin_amdgcn_mfma_f32_16x16x32_bf16(af[mt], w1f[nt][kc], acc1[mt][nt], 0, 0, 0);
        }
        // ssp + store to st1 in layer-2 A-layout (row=edge, col=filter)
        // C-layout: col=lane&15 (filter), row=quad*4+reg (edge)
        #pragma unroll
        for (int mt = 0; mt < 2; ++mt)
            #pragma unroll
            for (int nt = 0; nt < 2; ++nt)
                #pragma unroll
                for (int r = 0; r < 4; ++r) {
                    int m = mt * 16 + quad * 4 + r;
                    int n = wv * 32 + nt * 16 + col;
                    st1[m * 136 + n] = (ushort_t)f2bf(ssp_f(acc1[mt][nt][r]));
                }
        __syncthreads();

        // ---- layer 2: W = (t1 @ w2 + b2) * C ; msg = h[src]*W ; agg[dst] += msg ----
        f32x4 acc2[2][2];
        #pragma unroll
        for (int mt = 0; mt < 2; ++mt)
            #pragma unroll
            for (int nt = 0; nt < 2; ++nt)
                acc2[mt][nt] = f32x4{rb2[nt], rb2[nt], rb2[nt], rb2[nt]};
        #pragma unroll
        for (int kc = 0; kc < 4; ++kc) {
            bf16x8 af[2];
            #pragma unroll
            for (int mt = 0; mt < 2; ++mt)
                af[mt] = *reinterpret_cast<const bf16x8*>(&st1[(mt * 16 + col) * 136 + kc * 32 + quad * 8]);
            #pragma unroll
            for (int mt = 0; mt < 2; ++mt)
                #pragma unroll
                for (int nt = 0; nt < 2; ++nt)
                    acc2[mt][nt] = __builtin_amdgcn_mfma_f32_16x16x32_bf16(af[mt], w2f[nt][kc], acc2[mt][nt], 0, 0, 0);
        }
        // epilogue: cutoff * gather * scatter
        #pragma unroll
        for (int mt = 0; mt < 2; ++mt)
            #pragma unroll
            for (int nt = 0; nt < 2; ++nt)
                #pragma unroll
                for (int r = 0; r < 4; ++r) {
                    int ml = mt * 16 + quad * 4 + r;       // block-local edge
                    int n  = wv * 32 + nt * 16 + col;      // filter
                    float val = acc2[mt][nt][r] * sC[ml];
                    float hs  = h[(size_t)ssrc[ml] * NF + n];
                    atomicAdd(&agg[(size_t)sdst[ml] * NF + n], val * hs);
                }
    }
}

extern "C" void kernel_launch(void* const* d_in, const int* in_sizes, int n_in,
                              void* d_out, int out_size, void* d_ws, size_t ws_size,
                              hipStream_t stream) {
    const float* x    = (const float*)d_in[0];   // [20000,128] fp32
    const int*   eidx = (const int*)d_in[1];     // [2,640000] int32
    const float* ew   = (const float*)d_in[2];   // [640000] fp32
    const float* ea   = (const float*)d_in[3];   // [640000,50] fp32
    const float* w1   = (const float*)d_in[4];   // [50,128]
    const float* b1   = (const float*)d_in[5];   // [128]
    const float* w2   = (const float*)d_in[6];   // [128,128]
    const float* b2   = (const float*)d_in[7];   // [128]
    const float* l1w  = (const float*)d_in[8];   // [128,128]
    const float* l2w  = (const float*)d_in[9];   // [128,128]
    const float* l2b  = (const float*)d_in[10];  // [128]
    const float* lw   = (const float*)d_in[11];  // [128,128]
    const float* lb   = (const float*)d_in[12];  // [128]
    (void)in_sizes; (void)n_in; (void)out_size; (void)ws_size;

    float* h   = (float*)d_ws;                                    // 10.24 MB
    float* agg = (float*)((char*)d_ws + (size_t)NNODES * NF * 4);  // 10.24 MB
    float* tmp = h;  // h is dead after k_edge; reuse for the tail MLP

    hipLaunchKernelGGL(k_zero, dim3(2500), dim3(256), 0, stream, (float4*)agg);
    // h = x @ lin1_w
    hipLaunchKernelGGL((k_mm<false, false>), dim3(625), dim3(256), 0, stream,
                       x, l1w, (const float*)nullptr, h, NNODES);
    // fused edge MLP (MFMA) + CFConv scatter
    hipLaunchKernelGGL(k_edge, dim3(1000), dim3(256), 0, stream,
                       eidx, eidx + NEDGES, ew, ea, w1, b1, w2, b2, h, agg);
    // tmp = ssp(agg @ lin2_w + lin2_b)
    hipLaunchKernelGGL((k_mm<true, true>), dim3(625), dim3(256), 0, stream,
                       agg, l2w, l2b, tmp, NNODES);
    // out = tmp @ lin_w + lin_b   (fp32 output)
    hipLaunchKernelGGL((k_mm<false, true>), dim3(625), dim3(256), 0, stream,
                       tmp, lw, lb, (float*)d_out, NNODES);
}

// Round 4
// 587.850 us; speedup vs baseline: 2.5367x; 1.4963x over previous
//
#include <hip/hip_runtime.h>
#include <hip/hip_bf16.h>

#define NNODES 20000
#define NEDGES 640000
#define NB 50
#define NF 128

typedef unsigned int uint_t;
typedef unsigned short ushort_t;

typedef __bf16 bf16x8 __attribute__((ext_vector_type(8)));
typedef float f32x4 __attribute__((ext_vector_type(4)));

// fp32 -> bf16 bits (round to nearest even), returned in low 16 bits
__device__ __forceinline__ uint_t f2bf(float f) {
    uint_t u = __float_as_uint(f);
    return (u + 0x7fffu + ((u >> 16) & 1u)) >> 16;
}

// fast shifted softplus: hardware v_exp_f32 / v_log_f32 (~7 instrs)
__device__ __forceinline__ float ssp_f(float x) {
    float t = __expf(-fabsf(x));
    return fmaxf(x, 0.0f) + __logf(1.0f + t) - 0.6931471805599453f;
}

// ---------------- zero the aggregation buffer (capture-safe) ----------------
__global__ __launch_bounds__(256) void k_zero(float4* __restrict__ p) {
    int i = blockIdx.x * 256 + threadIdx.x;   // 2500*256 = 640000 float4 = 2.56M floats exactly
    p[i] = make_float4(0.f, 0.f, 0.f, 0.f);
}

// ---------------- node GEMM: Y = X @ W  (MFMA, 64-row tile) ----------------
__global__ __launch_bounds__(256) void k_node1(const float* __restrict__ X,
                                               const float* __restrict__ W,
                                               float* __restrict__ Y, int nrows)
{
    __shared__ alignas(16) ushort_t sx[64 * 136];
    const int tid  = threadIdx.x;
    const int wv   = tid >> 6, lane = tid & 63;
    const int col  = lane & 15, quad = lane >> 4;

    bf16x8 wf[2][4];
    #pragma unroll
    for (int nt = 0; nt < 2; ++nt) {
        int n = wv * 32 + nt * 16 + col;
        #pragma unroll
        for (int kc = 0; kc < 4; ++kc)
            #pragma unroll
            for (int j = 0; j < 8; ++j)
                wf[nt][kc][j] = (__bf16)W[(kc * 32 + quad * 8 + j) * NF + n];
    }

    const int rbase = blockIdx.x * 64;
    // stage 64 rows -> bf16 LDS (packed pair writes)
    for (int i = tid; i < 64 * 64; i += 256) {
        int r = i >> 6, c = i & 63;
        int gr = rbase + r;
        float2 v = (gr < nrows) ? *reinterpret_cast<const float2*>(&X[(size_t)gr * NF + 2 * c])
                                : make_float2(0.f, 0.f);
        reinterpret_cast<uint_t*>(sx)[r * 68 + c] = f2bf(v.x) | (f2bf(v.y) << 16);
    }
    __syncthreads();

    f32x4 acc[4][2] = {};
    #pragma unroll
    for (int kc = 0; kc < 4; ++kc) {
        bf16x8 af[4];
        #pragma unroll
        for (int mt = 0; mt < 4; ++mt)
            af[mt] = *reinterpret_cast<const bf16x8*>(&sx[(mt * 16 + col) * 136 + kc * 32 + quad * 8]);
        #pragma unroll
        for (int mt = 0; mt < 4; ++mt)
            #pragma unroll
            for (int nt = 0; nt < 2; ++nt)
                acc[mt][nt] = __builtin_amdgcn_mfma_f32_16x16x32_bf16(af[mt], wf[nt][kc], acc[mt][nt], 0, 0, 0);
    }
    #pragma unroll
    for (int mt = 0; mt < 4; ++mt)
        #pragma unroll
        for (int nt = 0; nt < 2; ++nt)
            #pragma unroll
            for (int r = 0; r < 4; ++r) {
                int row = rbase + mt * 16 + quad * 4 + r;
                if (row < nrows) Y[(size_t)row * NF + wv * 32 + nt * 16 + col] = acc[mt][nt][r];
            }
}

// ---------------- fused tail: out = ssp(X @ W1 + b1) @ W2 + b2 ----------------
__global__ __launch_bounds__(256) void k_tail(const float* __restrict__ X,
                                              const float* __restrict__ W1, const float* __restrict__ B1,
                                              const float* __restrict__ W2, const float* __restrict__ B2,
                                              float* __restrict__ Y, int nrows)
{
    __shared__ alignas(16) ushort_t sx[64 * 136];
    __shared__ alignas(16) ushort_t st[64 * 136];
    const int tid  = threadIdx.x;
    const int wv   = tid >> 6, lane = tid & 63;
    const int col  = lane & 15, quad = lane >> 4;

    bf16x8 wf1[2][4], wf2[2][4];
    float rb1[2], rb2[2];
    #pragma unroll
    for (int nt = 0; nt < 2; ++nt) {
        int n = wv * 32 + nt * 16 + col;
        rb1[nt] = B1[n]; rb2[nt] = B2[n];
        #pragma unroll
        for (int kc = 0; kc < 4; ++kc)
            #pragma unroll
            for (int j = 0; j < 8; ++j) {
                int k = kc * 32 + quad * 8 + j;
                wf1[nt][kc][j] = (__bf16)W1[k * NF + n];
                wf2[nt][kc][j] = (__bf16)W2[k * NF + n];
            }
    }

    const int rbase = blockIdx.x * 64;
    for (int i = tid; i < 64 * 64; i += 256) {
        int r = i >> 6, c = i & 63;
        int gr = rbase + r;
        float2 v = (gr < nrows) ? *reinterpret_cast<const float2*>(&X[(size_t)gr * NF + 2 * c])
                                : make_float2(0.f, 0.f);
        reinterpret_cast<uint_t*>(sx)[r * 68 + c] = f2bf(v.x) | (f2bf(v.y) << 16);
    }
    __syncthreads();

    // layer 1 + ssp -> st (bf16, A-layout row-major)
    f32x4 acc[4][2];
    #pragma unroll
    for (int mt = 0; mt < 4; ++mt)
        #pragma unroll
        for (int nt = 0; nt < 2; ++nt)
            acc[mt][nt] = f32x4{rb1[nt], rb1[nt], rb1[nt], rb1[nt]};
    #pragma unroll
    for (int kc = 0; kc < 4; ++kc) {
        bf16x8 af[4];
        #pragma unroll
        for (int mt = 0; mt < 4; ++mt)
            af[mt] = *reinterpret_cast<const bf16x8*>(&sx[(mt * 16 + col) * 136 + kc * 32 + quad * 8]);
        #pragma unroll
        for (int mt = 0; mt < 4; ++mt)
            #pragma unroll
            for (int nt = 0; nt < 2; ++nt)
                acc[mt][nt] = __builtin_amdgcn_mfma_f32_16x16x32_bf16(af[mt], wf1[nt][kc], acc[mt][nt], 0, 0, 0);
    }
    #pragma unroll
    for (int mt = 0; mt < 4; ++mt)
        #pragma unroll
        for (int nt = 0; nt < 2; ++nt)
            #pragma unroll
            for (int r = 0; r < 4; ++r)
                st[(mt * 16 + quad * 4 + r) * 136 + wv * 32 + nt * 16 + col] =
                    (ushort_t)f2bf(ssp_f(acc[mt][nt][r]));
    __syncthreads();

    // layer 2 -> Y
    f32x4 acc2[4][2];
    #pragma unroll
    for (int mt = 0; mt < 4; ++mt)
        #pragma unroll
        for (int nt = 0; nt < 2; ++nt)
            acc2[mt][nt] = f32x4{rb2[nt], rb2[nt], rb2[nt], rb2[nt]};
    #pragma unroll
    for (int kc = 0; kc < 4; ++kc) {
        bf16x8 af[4];
        #pragma unroll
        for (int mt = 0; mt < 4; ++mt)
            af[mt] = *reinterpret_cast<const bf16x8*>(&st[(mt * 16 + col) * 136 + kc * 32 + quad * 8]);
        #pragma unroll
        for (int mt = 0; mt < 4; ++mt)
            #pragma unroll
            for (int nt = 0; nt < 2; ++nt)
                acc2[mt][nt] = __builtin_amdgcn_mfma_f32_16x16x32_bf16(af[mt], wf2[nt][kc], acc2[mt][nt], 0, 0, 0);
    }
    #pragma unroll
    for (int mt = 0; mt < 4; ++mt)
        #pragma unroll
        for (int nt = 0; nt < 2; ++nt)
            #pragma unroll
            for (int r = 0; r < 4; ++r) {
                int row = rbase + mt * 16 + quad * 4 + r;
                if (row < nrows) Y[(size_t)row * NF + wv * 32 + nt * 16 + col] = acc2[mt][nt][r];
            }
}

// ---------------- fused edge MLP (MFMA) + CFConv gather/scatter ----------------
// 256 threads = 4 waves; wave owns 32 filters; 32 edges per iteration.
// Grid MUST be 2000 blocks: 2000 * 320 = 640000 edges, 10 iters of 32.
__global__ __launch_bounds__(256) void k_edge(
    const int* __restrict__ esrc, const int* __restrict__ edst,
    const float* __restrict__ ew, const float* __restrict__ ea,
    const float* __restrict__ w1, const float* __restrict__ b1,
    const float* __restrict__ w2, const float* __restrict__ b2,
    const float* __restrict__ h, float* __restrict__ agg)
{
    __shared__ alignas(16) ushort_t sea[32 * 72];    // [edge][k<64], pad 72
    __shared__ alignas(16) ushort_t st1[32 * 136];   // [edge][filter<128], pad 136
    __shared__ float sC[32];
    __shared__ int ssrc[32], sdst[32];

    const int tid  = threadIdx.x;
    const int wv   = tid >> 6, lane = tid & 63;
    const int col  = lane & 15, quad = lane >> 4;

    // zero sea once: k in [50,72) must stay 0 forever (staging only writes k<50)
    for (int i = tid; i < 32 * 72; i += 256) sea[i] = 0;

    // loop-invariant weight fragments (B-layout: lane holds B[k=quad*8+j][n=lane&15])
    bf16x8 w1f[2][2];
    bf16x8 w2f[2][4];
    float rb1[2], rb2[2];
    #pragma unroll
    for (int nt = 0; nt < 2; ++nt) {
        int n = wv * 32 + nt * 16 + col;
        rb1[nt] = b1[n]; rb2[nt] = b2[n];
        #pragma unroll
        for (int kc = 0; kc < 2; ++kc)
            #pragma unroll
            for (int j = 0; j < 8; ++j) {
                int k = kc * 32 + quad * 8 + j;
                w1f[nt][kc][j] = (__bf16)((k < NB) ? w1[k * NF + n] : 0.0f);
            }
        #pragma unroll
        for (int kc = 0; kc < 4; ++kc)
            #pragma unroll
            for (int j = 0; j < 8; ++j)
                w2f[nt][kc][j] = (__bf16)w2[(kc * 32 + quad * 8 + j) * NF + n];
    }

    const int e0 = blockIdx.x * 320;

    for (int it = 0; it < 10; ++it) {
        const int ebase = e0 + it * 32;
        __syncthreads();   // protect sea/st1/sC from previous iteration's readers
        for (int i = tid; i < 32 * NB; i += 256) {
            int e = i / NB;
            int k = i - e * NB;
            sea[e * 72 + k] = (ushort_t)f2bf(ea[(size_t)ebase * NB + i]);
        }
        if (tid < 32) {
            int e = ebase + tid;
            ssrc[tid] = esrc[e];
            sdst[tid] = edst[e];
            sC[tid]   = 0.5f * (cosf(ew[e] * 0.31415926535897931f) + 1.0f);
        }
        __syncthreads();

        // hoisted gathers: only need ssrc; latency hides behind L1+ssp+L2
        float hg[2][2][4];
        #pragma unroll
        for (int mt = 0; mt < 2; ++mt)
            #pragma unroll
            for (int nt = 0; nt < 2; ++nt)
                #pragma unroll
                for (int r = 0; r < 4; ++r) {
                    int ml = mt * 16 + quad * 4 + r;
                    hg[mt][nt][r] = h[(size_t)ssrc[ml] * NF + wv * 32 + nt * 16 + col];
                }

        // layer 1: t1 = ssp(ea @ w1 + b1)
        f32x4 acc1[2][2];
        #pragma unroll
        for (int mt = 0; mt < 2; ++mt)
            #pragma unroll
            for (int nt = 0; nt < 2; ++nt)
                acc1[mt][nt] = f32x4{rb1[nt], rb1[nt], rb1[nt], rb1[nt]};
        #pragma unroll
        for (int kc = 0; kc < 2; ++kc) {
            bf16x8 af[2];
            #pragma unroll
            for (int mt = 0; mt < 2; ++mt)
                af[mt] = *reinterpret_cast<const bf16x8*>(&sea[(mt * 16 + col) * 72 + kc * 32 + quad * 8]);
            #pragma unroll
            for (int mt = 0; mt < 2; ++mt)
                #pragma unroll
                for (int nt = 0; nt < 2; ++nt)
                    acc1[mt][nt] = __builtin_amdgcn_mfma_f32_16x16x32_bf16(af[mt], w1f[nt][kc], acc1[mt][nt], 0, 0, 0);
        }
        #pragma unroll
        for (int mt = 0; mt < 2; ++mt)
            #pragma unroll
            for (int nt = 0; nt < 2; ++nt)
                #pragma unroll
                for (int r = 0; r < 4; ++r)
                    st1[(mt * 16 + quad * 4 + r) * 136 + wv * 32 + nt * 16 + col] =
                        (ushort_t)f2bf(ssp_f(acc1[mt][nt][r]));
        __syncthreads();

        // layer 2 + epilogue
        f32x4 acc2[2][2];
        #pragma unroll
        for (int mt = 0; mt < 2; ++mt)
            #pragma unroll
            for (int nt = 0; nt < 2; ++nt)
                acc2[mt][nt] = f32x4{rb2[nt], rb2[nt], rb2[nt], rb2[nt]};
        #pragma unroll
        for (int kc = 0; kc < 4; ++kc) {
            bf16x8 af[2];
            #pragma unroll
            for (int mt = 0; mt < 2; ++mt)
                af[mt] = *reinterpret_cast<const bf16x8*>(&st1[(mt * 16 + col) * 136 + kc * 32 + quad * 8]);
            #pragma unroll
            for (int mt = 0; mt < 2; ++mt)
                #pragma unroll
                for (int nt = 0; nt < 2; ++nt)
                    acc2[mt][nt] = __builtin_amdgcn_mfma_f32_16x16x32_bf16(af[mt], w2f[nt][kc], acc2[mt][nt], 0, 0, 0);
        }
        #pragma unroll
        for (int mt = 0; mt < 2; ++mt)
            #pragma unroll
            for (int nt = 0; nt < 2; ++nt)
                #pragma unroll
                for (int r = 0; r < 4; ++r) {
                    int ml = mt * 16 + quad * 4 + r;
                    float val = acc2[mt][nt][r] * sC[ml];
                    atomicAdd(&agg[(size_t)sdst[ml] * NF + wv * 32 + nt * 16 + col], val * hg[mt][nt][r]);
                }
    }
}

extern "C" void kernel_launch(void* const* d_in, const int* in_sizes, int n_in,
                              void* d_out, int out_size, void* d_ws, size_t ws_size,
                              hipStream_t stream) {
    const float* x    = (const float*)d_in[0];   // [20000,128] fp32
    const int*   eidx = (const int*)d_in[1];     // [2,640000] int32
    const float* ew   = (const float*)d_in[2];   // [640000]
    const float* ea   = (const float*)d_in[3];   // [640000,50]
    const float* w1   = (const float*)d_in[4];   // [50,128]
    const float* b1   = (const float*)d_in[5];   // [128]
    const float* w2   = (const float*)d_in[6];   // [128,128]
    const float* b2   = (const float*)d_in[7];   // [128]
    const float* l1w  = (const float*)d_in[8];   // [128,128]
    const float* l2w  = (const float*)d_in[9];   // [128,128]
    const float* l2b  = (const float*)d_in[10];  // [128]
    const float* lw   = (const float*)d_in[11];  // [128,128]
    const float* lb   = (const float*)d_in[12];  // [128]
    (void)in_sizes; (void)n_in; (void)out_size; (void)ws_size;

    float* h   = (float*)d_ws;                                    // 10.24 MB
    float* agg = (float*)((char*)d_ws + (size_t)NNODES * NF * 4);  // 10.24 MB

    hipLaunchKernelGGL(k_zero, dim3(2500), dim3(256), 0, stream, (float4*)agg);
    // h = x @ lin1_w  (MFMA)
    hipLaunchKernelGGL(k_node1, dim3(313), dim3(256), 0, stream, x, l1w, h, NNODES);
    // fused edge MLP (MFMA) + CFConv scatter
    hipLaunchKernelGGL(k_edge, dim3(2000), dim3(256), 0, stream,
                       eidx, eidx + NEDGES, ew, ea, w1, b1, w2, b2, h, agg);
    // out = ssp(agg @ lin2_w + lin2_b) @ lin_w + lin_b  (fused MFMA)
    hipLaunchKernelGGL(k_tail, dim3(313), dim3(256), 0, stream,
                       agg, l2w, l2b, lw, lb, (float*)d_out, NNODES);
}